// Round 12
// baseline (242.556 us; speedup 1.0000x reference)
//
#include <hip/hip_runtime.h>

// EfficientCrossAttentionHead: B=4, N=16384, C=256, H=64, fp32 in/out.
//   kW_pack : weights -> bf16 MFMA B-fragment layout in ws
//   kP_proj : 4 tiles x 64 tokens per block (grid 64x8, 4 waves);
//             waves split by TOKEN ROWS (all waves share identical weight
//             fragment addresses -> L1-hot, no L2 re-fetch); T14 full-tile
//             register relay; MFMA -> k|q|v; fused P^T V; q/partials out.
//   kB_reduce: bf16 partials + pz -> w[bs][64][64] f32
//   kC_out  : out = softmax_row(q_s) @ w_{1-s}  (MFMA, bf16 in / f32 acc)
// ws usage ~34.5 MB.

#define B_ 4
#define N_ 16384
#define C_ 256

typedef float f32x4 __attribute__((ext_vector_type(4)));
typedef __bf16 bf16x8 __attribute__((ext_vector_type(8)));
typedef __bf16 bf16x4v __attribute__((ext_vector_type(4)));
typedef unsigned short us8 __attribute__((ext_vector_type(8)));

__device__ __forceinline__ unsigned short f2bf(float f) {
  union { float f; unsigned u; } v; v.f = f;
  return (unsigned short)((v.u + 0x7FFFu + ((v.u >> 16) & 1u)) >> 16);
}
__device__ __forceinline__ float bf2f(unsigned short h) {
  union { unsigned u; float f; } v; v.u = ((unsigned)h) << 16;
  return v.f;
}

// LDS-only sync: waits local ops, does NOT drain vmcnt -> relay global loads
// stay in flight across barriers.
__device__ __forceinline__ void sync_lds() {
  asm volatile("s_waitcnt lgkmcnt(0)" ::: "memory");
  __builtin_amdgcn_sched_barrier(0);
  __builtin_amdgcn_s_barrier();
  __builtin_amdgcn_sched_barrier(0);
}

// ws byte offsets
#define WPACK_OFF 0u           // [2][12][8][64][8] bf16 = 196608 B
#define Q_OFF     262144u      // q logits bf16 [8][16384][64] = 16 MB
#define PNW_OFF   17039360u    // partial nw bf16 [8][64][4096] = 4 MB
#define PZ_OFF    33816576u    // z f32 [8][256][64] = 512 KB
#define WFIN_OFF  34340864u    // w final [8][4096] f32 = 128 KB

__global__ __launch_bounds__(256) void kW_pack(
    const float* __restrict__ Wk0, const float* __restrict__ Wk1,
    const float* __restrict__ Wq0, const float* __restrict__ Wq1,
    const float* __restrict__ Wv0, const float* __restrict__ Wv1,
    unsigned short* __restrict__ wpack) {
  int t = blockIdx.x * 256 + threadIdx.x;  // [0, 98304)
  int i = t & 7;
  int lane = (t >> 3) & 63;
  int q = t >> 9;            // [0,192)
  int ks = q & 7;
  int sj = q >> 3;           // [0,24)
  int s = sj / 12;
  int j = sj - s * 12;       // col-frag 0..11 (k:0-3, q:4-7, v:8-11)
  int gc = 16 * j + (lane & 15);
  int c = 32 * ks + ((lane >> 4) << 3) + i;
  int m = gc >> 6, row = gc & 63;
  const float* W;
  if (s == 0) W = (m == 0) ? Wk0 : (m == 1) ? Wq0 : Wv0;
  else        W = (m == 0) ? Wk1 : (m == 1) ? Wq1 : Wv1;
  wpack[t] = f2bf(W[row * 256 + c]);
}

// 4 tiles x 64 tokens per block; 4 waves; wave w = token rows [16w,16w+16)
// of each tile, computing ALL 12 output col-frags (shared weight addresses).
__global__ __launch_bounds__(256, 2) void kP_proj(
    const float* __restrict__ x0, const float* __restrict__ x1,
    const unsigned short* __restrict__ wpack,
    unsigned short* __restrict__ qbuf, unsigned short* __restrict__ pnw,
    float* __restrict__ pz) {
  int slot = blockIdx.x;     // 0..63 -> tokens [slot*256, slot*256+256)
  int bs = blockIdx.y;       // b = bs>>1, s = bs&1
  int b = bs >> 1, s = bs & 1;
  const float* x = (s ? x1 : x0) + (size_t)b * N_ * C_;
  int t = threadIdx.x;       // 0..255
  int w = t >> 6;            // wave 0..3
  int l = t & 63;
  int l15 = l & 15, lg = l >> 4;

  // LDS: xsb bf16 [64 tok][256] swizzled (32K) | pT [64 h][64 n] pitch144
  // (9216) | vT same | qs [64][64] swz (8K) = 59392 B.
  __shared__ __align__(16) char lds[59392];
  char* xsb = lds;
  char* pTb = lds + 32768;
  char* vTb = lds + 41984;
  char* qsb = lds + 51200;

  const char* wbase = (const char*)wpack + (size_t)s * 12 * 8 * 64 * 16;

  f32x4 nwacc[4];
#pragma unroll
  for (int df = 0; df < 4; ++df) { f32x4 z = {0.f,0.f,0.f,0.f}; nwacc[df] = z; }
  float zacc[4] = {0.f, 0.f, 0.f, 0.f};

  // prologue: stage tile 0 (streaming, bounded live regs)
  {
    const f32x4* xsrc = (const f32x4*)(x + (size_t)(slot * 256) * C_);
#pragma unroll 1
    for (int g2 = 0; g2 < 4; ++g2) {
#pragma unroll
      for (int i = 0; i < 4; ++i) {
        int f = t + 256 * (g2 * 4 + i);   // 8B-chunk id; row = f>>6
        int row = f >> 6;
        f32x4 v = xsrc[f];
        bf16x4v pk;
        pk[0] = (__bf16)v[0]; pk[1] = (__bf16)v[1];
        pk[2] = (__bf16)v[2]; pk[3] = (__bf16)v[3];
        int off = (f * 8) ^ ((row & 7) << 4);
        *(bf16x4v*)(xsb + off) = pk;
      }
    }
  }
  sync_lds();

  for (int it = 0; it < 4; ++it) {
    int n0 = slot * 256 + it * 64;

    // T14 relay: issue next tile's 16 f32x4 loads now; latency hides under
    // proj (96 MFMA) + repack + PV; written to LDS after PV.
    f32x4 pf[16];
    if (it < 3) {
      const f32x4* xn = (const f32x4*)(x + (size_t)(n0 + 64) * C_);
#pragma unroll
      for (int i = 0; i < 16; ++i) pf[i] = xn[t + 256 * i];
    }

    // proj: wave w rows [16w,16w+16) x ALL 192 cols. ONE a-frag read per ks;
    // 12 bfr loads per ks with addresses IDENTICAL across waves (L1-hot).
    f32x4 acc[12];
#pragma unroll
    for (int jj = 0; jj < 12; ++jj) { f32x4 z = {0.f,0.f,0.f,0.f}; acc[jj] = z; }

#pragma unroll
    for (int ks = 0; ks < 8; ++ks) {
      int row = w * 16 + l15;
      int aoff = (row * 512 + ks * 64 + lg * 16) ^ ((row & 7) << 4);
      bf16x8 a = *(const bf16x8*)(xsb + aoff);
#pragma unroll
      for (int jj = 0; jj < 12; ++jj) {
        bf16x8 bfr = *(const bf16x8*)(wbase + (((size_t)(jj * 8 + ks)) * 64 + l) * 16);
        acc[jj] = __builtin_amdgcn_mfma_f32_16x16x32_bf16(a, bfr, acc[jj], 0, 0, 0);
      }
    }
    sync_lds();   // xsb reads done

    // repack. token n = w*16 + lg*4 + r (this wave's 16 rows)
    int nb2 = (w * 16 + lg * 4) * 2;     // byte offset of token group in a row
    {  // k cols (jj 0..3): exp -> pT[h][n] pitch 144, + z[h]
#pragma unroll
      for (int jj = 0; jj < 4; ++jj) {
        int h = jj * 16 + l15;
        float e0 = __expf(acc[jj][0]), e1 = __expf(acc[jj][1]);
        float e2 = __expf(acc[jj][2]), e3 = __expf(acc[jj][3]);
        float zl = e0 + e1 + e2 + e3;
        bf16x4v pk;
        pk[0] = (__bf16)e0; pk[1] = (__bf16)e1;
        pk[2] = (__bf16)e2; pk[3] = (__bf16)e3;
        *(bf16x4v*)(pTb + h * 144 + nb2) = pk;
        zl += __shfl_xor(zl, 16);
        zl += __shfl_xor(zl, 32);
        zacc[jj] += zl;
      }
    }
    {  // q cols (jj 4..7): bf16 -> qs [n][64 h] swizzled
#pragma unroll
      for (int jj = 4; jj < 8; ++jj) {
        int col = (jj - 4) * 16 + l15;
#pragma unroll
        for (int r = 0; r < 4; ++r) {
          int n = w * 16 + lg * 4 + r;
          int off = (n * 128 + col * 2) ^ ((n & 7) << 4);
          *(__bf16*)(qsb + off) = (__bf16)acc[jj][r];
        }
      }
    }
    {  // v cols (jj 8..11): -> vT[d][n] pitch 144
#pragma unroll
      for (int jj = 8; jj < 12; ++jj) {
        int d = (jj - 8) * 16 + l15;
        bf16x4v pk;
        pk[0] = (__bf16)acc[jj][0]; pk[1] = (__bf16)acc[jj][1];
        pk[2] = (__bf16)acc[jj][2]; pk[3] = (__bf16)acc[jj][3];
        *(bf16x4v*)(vTb + d * 144 + nb2) = pk;
      }
    }
    sync_lds();   // overlays ready

    // q readout: coalesced (4096 shorts, 2 x 16B/thread)
    {
      unsigned short* qg = qbuf + ((size_t)bs * N_ + n0) * 64;
#pragma unroll
      for (int r2 = 0; r2 < 2; ++r2) {
        int idx = t + 256 * r2;       // us8 chunk, [0,512)
        int n = idx >> 3, c = idx & 7;
        int off = (n * 128 + c * 16) ^ ((n & 7) << 4);
        us8 v = *(const us8*)(qsb + off);
        *(us8*)(qg + (size_t)idx * 8) = v;
      }
    }

    // fused P^T V (K=64, 2 k-steps); wave w -> h-frag w
#pragma unroll
    for (int k2 = 0; k2 < 2; ++k2) {
      bf16x8 a2 = *(const bf16x8*)(pTb + (w * 16 + l15) * 144 + k2 * 64 + lg * 16);
#pragma unroll
      for (int df = 0; df < 4; ++df) {
        bf16x8 b2 = *(const bf16x8*)(vTb + (df * 16 + l15) * 144 + k2 * 64 + lg * 16);
        nwacc[df] = __builtin_amdgcn_mfma_f32_16x16x32_bf16(a2, b2, nwacc[df], 0, 0, 0);
      }
    }

    // T14 write-late: relay regs -> xsb (disjoint from pT/vT/qs readers)
    if (it < 3) {
#pragma unroll
      for (int i = 0; i < 16; ++i) {
        int f = t + 256 * i;
        int row = f >> 6;
        bf16x4v pk;
        pk[0] = (__bf16)pf[i][0]; pk[1] = (__bf16)pf[i][1];
        pk[2] = (__bf16)pf[i][2]; pk[3] = (__bf16)pf[i][3];
        int off = (f * 8) ^ ((row & 7) << 4);
        *(bf16x4v*)(xsb + off) = pk;
      }
    }
    sync_lds();   // next proj reads xsb; PV reads all done
  }

  // write partials: nw bf16 [bs][64][4096], z f32 rows [bs][slot*4+w][64]
  {
    size_t base = ((size_t)bs * 64 + slot) * 4096;
#pragma unroll
    for (int df = 0; df < 4; ++df)
#pragma unroll
      for (int r = 0; r < 4; ++r) {
        int h = w * 16 + lg * 4 + r;
        int d = df * 16 + l15;
        pnw[base + h * 64 + d] = f2bf(nwacc[df][r]);
      }
  }
  if (lg == 0) {
    size_t zr = ((size_t)bs * 256 + slot * 4 + w) * 64;
#pragma unroll
    for (int jj = 0; jj < 4; ++jj)
      pz[zr + jj * 16 + l15] = zacc[jj];
  }
}

__global__ __launch_bounds__(256) void kB_reduce(
    const unsigned short* __restrict__ pnw, const float* __restrict__ pz,
    float* __restrict__ wfin) {
  int g = blockIdx.x;   // 0..15: idx range [g*256,g*256+256) => h in [g*4,g*4+4)
  int bs = blockIdx.y;  // 0..7
  int t = threadIdx.x;
  int wv = t >> 6, l = t & 63;
  __shared__ float zinv[4];
  int h = g * 4 + wv;
  float z = 0.f;
#pragma unroll
  for (int j = 0; j < 4; ++j)
    z += pz[((size_t)bs * 256 + l + 64 * j) * 64 + h];
#pragma unroll
  for (int m = 32; m; m >>= 1) z += __shfl_xor(z, m);
  if (l == 0) zinv[wv] = 1.f / z;
  __syncthreads();
  int idx = g * 256 + t;
  float ssum = 0.f;
#pragma unroll 8
  for (int p = 0; p < 64; ++p)
    ssum += bf2f(pnw[((size_t)bs * 64 + p) * 4096 + idx]);
  wfin[(size_t)bs * 4096 + idx] = ssum * zinv[wv];
}

__global__ __launch_bounds__(256) void kC_out(
    const unsigned short* __restrict__ qbuf, const float* __restrict__ wfin,
    float* __restrict__ out) {
  int bs = blockIdx.y, b = bs >> 1, s = bs & 1;
  int t = threadIdx.x;
  int w = t >> 6, l = t & 63;
  int l15 = l & 15, lg = l >> 4;
  int tok0 = blockIdx.x * 64;

  __shared__ __align__(16) char cb[16384];
  char* plb = cb;            // P bf16 [64 tok][64 h], swizzled (8K)
  char* wlb = cb + 8192;     // W^T bf16 [64 d][64 h], swizzled (8K)
  float* ob = (float*)cb;    // out f32 [64 tok][64 d] (16K, aliases after MFMA)

  // 1. load w_{1-s}, transpose to [d][h] bf16 swizzled — all 4096 elements
  const float* wsrc = wfin + (size_t)(b * 2 + (1 - s)) * 4096;
#pragma unroll
  for (int rr = 0; rr < 4; ++rr) {
    int fi = t + 256 * rr;        // f32x4 chunk id, [0,1024)
    int h = fi >> 4, d4 = (fi & 15) * 4;
    f32x4 v = *(const f32x4*)(wsrc + h * 64 + d4);
#pragma unroll
    for (int e = 0; e < 4; ++e) {
      int d = d4 + e;
      int off = (d * 128 + h * 2) ^ ((d & 7) << 4);
      *(unsigned short*)(wlb + off) = f2bf(v[e]);
    }
  }

  // 2. q row: exp, quad-reduce sum, normalize, bf16 -> pl
  {
    int tl = t >> 2, p4 = t & 3;
    const unsigned short* qr =
        qbuf + ((size_t)bs * N_ + tok0 + tl) * 64 + p4 * 16;
    us8 u0 = *(const us8*)(qr);
    us8 u1 = *(const us8*)(qr + 8);
    float e[16]; float sum = 0.f;
#pragma unroll
    for (int i = 0; i < 8; ++i) { e[i] = __expf(bf2f(u0[i])); sum += e[i]; }
#pragma unroll
    for (int i = 0; i < 8; ++i) { e[8+i] = __expf(bf2f(u1[i])); sum += e[8+i]; }
    sum += __shfl_xor(sum, 1);
    sum += __shfl_xor(sum, 2);
    float inv = 1.f / sum;
    us8 p0, p1;
#pragma unroll
    for (int i = 0; i < 8; ++i) { p0[i] = f2bf(e[i] * inv); p1[i] = f2bf(e[8+i] * inv); }
    int off = (tl * 128 + p4 * 32) ^ ((tl & 7) << 4);
    *(us8*)(plb + off) = p0;
    *(us8*)(plb + (off ^ 16)) = p1;   // +16 within same 32B chunk (p4*32 has bit4=0)
  }
  __syncthreads();

  // 3. out[64 tok][64 d] = P @ W^T' : 2 K-steps of 16x16x32 MFMA
  f32x4 acc[4];
#pragma unroll
  for (int rf = 0; rf < 4; ++rf) { f32x4 z = {0.f,0.f,0.f,0.f}; acc[rf] = z; }
#pragma unroll
  for (int k2 = 0; k2 < 2; ++k2) {
    int dd = w * 16 + l15;
    int boff = (dd * 128 + (k2 * 32 + lg * 8) * 2) ^ ((dd & 7) << 4);
    bf16x8 bfrag = *(const bf16x8*)(wlb + boff);
#pragma unroll
    for (int rf = 0; rf < 4; ++rf) {
      int row = rf * 16 + l15;
      int aoff = (row * 128 + (k2 * 32 + lg * 8) * 2) ^ ((row & 7) << 4);
      bf16x8 afrag = *(const bf16x8*)(plb + aoff);
      acc[rf] = __builtin_amdgcn_mfma_f32_16x16x32_bf16(afrag, bfrag, acc[rf], 0, 0, 0);
    }
  }
  __syncthreads();   // pl/wl dead; ob takes over

  // 4. fragments -> ob
#pragma unroll
  for (int rf = 0; rf < 4; ++rf)
#pragma unroll
    for (int r = 0; r < 4; ++r) {
      int tok = rf * 16 + lg * 4 + r;
      int d = w * 16 + l15;
      ob[tok * 64 + d] = acc[rf][r];
    }
  __syncthreads();

  // 5. coalesced f32x4 store
  float* outp = out + (size_t)s * ((size_t)B_ * N_ * 64) +
                ((size_t)b * N_ + tok0) * 64;
#pragma unroll
  for (int r2 = 0; r2 < 4; ++r2) {
    int fi = t + 256 * r2;   // 0..1023 f32x4 chunks
    ((f32x4*)outp)[fi] = ((const f32x4*)ob)[fi];
  }
}

extern "C" void kernel_launch(void* const* d_in, const int* in_sizes, int n_in,
                              void* d_out, int out_size, void* d_ws, size_t ws_size,
                              hipStream_t stream) {
  const float* x0  = (const float*)d_in[0];
  const float* x1  = (const float*)d_in[1];
  const float* Wk0 = (const float*)d_in[2];
  const float* Wk1 = (const float*)d_in[3];
  const float* Wq0 = (const float*)d_in[4];
  const float* Wq1 = (const float*)d_in[5];
  const float* Wv0 = (const float*)d_in[6];
  const float* Wv1 = (const float*)d_in[7];
  float* out = (float*)d_out;
  char* wsb = (char*)d_ws;
  unsigned short* wpack = (unsigned short*)(wsb + WPACK_OFF);
  unsigned short* qbuf  = (unsigned short*)(wsb + Q_OFF);
  unsigned short* pnw   = (unsigned short*)(wsb + PNW_OFF);
  float* pz   = (float*)(wsb + PZ_OFF);
  float* wfin = (float*)(wsb + WFIN_OFF);

  kW_pack<<<dim3(384), dim3(256), 0, stream>>>(Wk0, Wk1, Wq0, Wq1, Wv0, Wv1, wpack);
  kP_proj<<<dim3(64, 8), dim3(256), 0, stream>>>(x0, x1, wpack, qbuf, pnw, pz);
  kB_reduce<<<dim3(16, 8), dim3(256), 0, stream>>>(pnw, pz, wfin);
  kC_out<<<dim3(256, 8), dim3(256), 0, stream>>>(qbuf, wfin, out);
}

// Round 15
// 52.429 us; speedup vs baseline: 4.6264x; 4.6264x over previous
//
#include <hip/hip_runtime.h>

// EfficientCrossAttentionHead: B=4, N=16384, C=256, H=64, fp32 in/out.
//   kW_pack : weights -> bf16 MFMA B-fragment layout in ws
//   kP_proj : 8 tiles x 32 tokens per block (grid 64x8, 4 waves, all blocks
//             resident); weight frags PINNED in VGPRs (asm anti-remat);
//             x staged f32 via global_load_lds, double-buffered; vmcnt(0)
//             drain at tile boundary (r14's vmcnt(2) left the 8th DMA
//             outstanding -> stale rows); MFMA -> k|q|v; fused P^T V.
//   kB_reduce: bf16 partials + pz -> w[bs][64][64] f32
//   kC_out  : out = softmax_row(q_s) @ w_{1-s}  (MFMA, bf16 in / f32 acc)

#define B_ 4
#define N_ 16384
#define C_ 256

typedef float f32x4 __attribute__((ext_vector_type(4)));
typedef __bf16 bf16x8 __attribute__((ext_vector_type(8)));
typedef __bf16 bf16x4v __attribute__((ext_vector_type(4)));
typedef unsigned short us8 __attribute__((ext_vector_type(8)));

__device__ __forceinline__ unsigned short f2bf(float f) {
  union { float f; unsigned u; } v; v.f = f;
  return (unsigned short)((v.u + 0x7FFFu + ((v.u >> 16) & 1u)) >> 16);
}
__device__ __forceinline__ float bf2f(unsigned short h) {
  union { unsigned u; float f; } v; v.u = ((unsigned)h) << 16;
  return v.f;
}

// LDS-only sync: does NOT drain vmcnt (DMA/stores stay in flight).
__device__ __forceinline__ void sync_lds() {
  asm volatile("s_waitcnt lgkmcnt(0)" ::: "memory");
  __builtin_amdgcn_sched_barrier(0);
  __builtin_amdgcn_s_barrier();
  __builtin_amdgcn_sched_barrier(0);
}

__device__ __forceinline__ void load_lds16(const void* g, void* l) {
  __builtin_amdgcn_global_load_lds(
      (const __attribute__((address_space(1))) unsigned int*)g,
      (__attribute__((address_space(3))) unsigned int*)l, 16, 0, 0);
}

// ws byte offsets
#define WPACK_OFF 0u           // [2][12][8][64][8] bf16 = 196608 B
#define Q_OFF     262144u      // q logits bf16 [8][16384][64] = 16 MB
#define PNW_OFF   17039360u    // partial nw bf16 [8][64][4096] = 4 MB
#define PZ_OFF    33816576u    // z f32 [8][64][64] = 128 KB
#define WFIN_OFF  34340864u    // w final [8][4096] f32 = 128 KB

__global__ __launch_bounds__(256) void kW_pack(
    const float* __restrict__ Wk0, const float* __restrict__ Wk1,
    const float* __restrict__ Wq0, const float* __restrict__ Wq1,
    const float* __restrict__ Wv0, const float* __restrict__ Wv1,
    unsigned short* __restrict__ wpack) {
  int t = blockIdx.x * 256 + threadIdx.x;  // [0, 98304)
  int i = t & 7;
  int lane = (t >> 3) & 63;
  int q = t >> 9;            // [0,192)
  int ks = q & 7;
  int sj = q >> 3;           // [0,24)
  int s = sj / 12;
  int j = sj - s * 12;       // col-frag 0..11 (k:0-3, q:4-7, v:8-11)
  int gc = 16 * j + (lane & 15);
  int c = 32 * ks + ((lane >> 4) << 3) + i;
  int m = gc >> 6, row = gc & 63;
  const float* W;
  if (s == 0) W = (m == 0) ? Wk0 : (m == 1) ? Wq0 : Wv0;
  else        W = (m == 0) ? Wk1 : (m == 1) ? Wq1 : Wv1;
  wpack[t] = f2bf(W[row * 256 + c]);
}

// 8 tiles x 32 tokens per block; 4 waves; wave w: cols j in {w, w+4, w+8}
__global__ __launch_bounds__(256, 2) void kP_proj(
    const float* __restrict__ x0, const float* __restrict__ x1,
    const unsigned short* __restrict__ wpack,
    unsigned short* __restrict__ qbuf, unsigned short* __restrict__ pnw,
    float* __restrict__ pz) {
  int slot = blockIdx.x;     // 0..63 -> tokens [slot*256, slot*256+256)
  int bs = blockIdx.y;       // b = bs>>1, s = bs&1
  int b = bs >> 1, s = bs & 1;
  const float* x = (s ? x1 : x0) + (size_t)b * N_ * C_;
  int t = threadIdx.x;       // 0..255
  int w = t >> 6;            // wave 0..3
  int l = t & 63;
  int l15 = l & 15, lg = l >> 4;

  // LDS: xfA/xfB f32 [32][256] swizzled (2x32K) | pT bf16 [64][32] pitch80
  // (5120) | vT same | qs bf16 [32][64] swz (4K)  = 79872 B (2 blocks/CU).
  __shared__ __align__(16) char lds[79872];
  char* xfA = lds;               // scalar LDS pointers (no pointer array:
  char* xfB = lds + 32768;       //  addrspacecast static-init is rejected)
  char* pTb = lds + 65536;
  char* vTb = lds + 70656;
  char* qsb = lds + 75776;

  const char* wbase = (const char*)wpack + (size_t)s * 12 * 8 * 64 * 16;

  // weight B-fragments: load once, PIN in VGPRs (asm blocks rematerialization)
  bf16x8 bfr[3][8];
#pragma unroll
  for (int jj = 0; jj < 3; ++jj)
#pragma unroll
    for (int ks = 0; ks < 8; ++ks)
      bfr[jj][ks] = *(const bf16x8*)(wbase + (((size_t)((w + 4*jj)*8 + ks))*64 + l)*16);
#pragma unroll
  for (int jj = 0; jj < 3; ++jj)
#pragma unroll
    for (int ks = 0; ks < 8; ++ks)
      asm volatile("" : "+v"(bfr[jj][ks]));

  f32x4 nwacc[4];
#pragma unroll
  for (int df = 0; df < 4; ++df) { f32x4 z = {0.f,0.f,0.f,0.f}; nwacc[df] = z; }
  float zacc = 0.f;

  // STAGE(tile -> buf): 8 global_load_lds_dwordx4 / thread. LDS dest linear;
  // global source pre-swizzled by involution off^((row&7)<<4), row=off>>10.
  auto STAGE = [&](int tile, char* buf) {
    int nn0 = slot * 256 + tile * 32;
    const char* xgb = (const char*)(x + (size_t)nn0 * C_);
#pragma unroll
    for (int i = 0; i < 8; ++i) {
      int f = t + 256 * i;            // 16B chunk id, [0,2048); row = f>>6
      int row = f >> 6;
      int srcoff = (f * 16) ^ ((row & 7) << 4);
      load_lds16(xgb + srcoff, buf + f * 16);
    }
  };

  STAGE(0, xfA);
  asm volatile("s_waitcnt vmcnt(0)" ::: "memory");
  sync_lds();

#pragma unroll 1
  for (int it = 0; it < 8; ++it) {
    int n0 = slot * 256 + it * 32;
    char* xb = (it & 1) ? xfB : xfA;
    char* xn = (it & 1) ? xfA : xfB;

    if (it < 7) STAGE(it + 1, xn);   // issue only; rides under compute

    // proj: [32 tok][256] @ [256][192] -> k|q|v, weights pinned in regs
    f32x4 acc[2][3];
#pragma unroll
    for (int rf = 0; rf < 2; ++rf)
#pragma unroll
      for (int jj = 0; jj < 3; ++jj) { f32x4 z = {0.f,0.f,0.f,0.f}; acc[rf][jj] = z; }

#pragma unroll
    for (int ks = 0; ks < 8; ++ks) {
      bf16x8 a[2];
#pragma unroll
      for (int rf = 0; rf < 2; ++rf) {
        int row = rf * 16 + l15;
        int off = row * 1024 + ks * 128 + lg * 32;
        int so = off ^ ((row & 7) << 4);
        f32x4 v0 = *(const f32x4*)(xb + so);
        f32x4 v1 = *(const f32x4*)(xb + (so ^ 16));
        bf16x8 av;
        av[0] = (__bf16)v0[0]; av[1] = (__bf16)v0[1];
        av[2] = (__bf16)v0[2]; av[3] = (__bf16)v0[3];
        av[4] = (__bf16)v1[0]; av[5] = (__bf16)v1[1];
        av[6] = (__bf16)v1[2]; av[7] = (__bf16)v1[3];
        a[rf] = av;
      }
#pragma unroll
      for (int jj = 0; jj < 3; ++jj)
#pragma unroll
        for (int rf = 0; rf < 2; ++rf)
          acc[rf][jj] = __builtin_amdgcn_mfma_f32_16x16x32_bf16(
              a[rf], bfr[jj][ks], acc[rf][jj], 0, 0, 0);
    }
    sync_lds();   // proj ds_reads done; overlays writable (prev PV done)

    // repack. token n = rf*16 + lg*4 + r
    {  // k: exp -> pT bf16 [h][32] pitch 80, + z
      int hcol = w * 16 + l15;
      float zl = 0.f;
#pragma unroll
      for (int rf = 0; rf < 2; ++rf) {
        float e0 = __expf(acc[rf][0][0]), e1 = __expf(acc[rf][0][1]);
        float e2 = __expf(acc[rf][0][2]), e3 = __expf(acc[rf][0][3]);
        zl += e0 + e1 + e2 + e3;
        bf16x4v pk;
        pk[0] = (__bf16)e0; pk[1] = (__bf16)e1;
        pk[2] = (__bf16)e2; pk[3] = (__bf16)e3;
        *(bf16x4v*)(pTb + hcol * 80 + (rf * 16 + lg * 4) * 2) = pk;
      }
      zl += __shfl_xor(zl, 16);
      zl += __shfl_xor(zl, 32);
      zacc += zl;
    }
    {  // v -> vT bf16 [d][32] pitch 80
      int dcol = w * 16 + l15;
#pragma unroll
      for (int rf = 0; rf < 2; ++rf) {
        bf16x4v pk;
        pk[0] = (__bf16)acc[rf][2][0]; pk[1] = (__bf16)acc[rf][2][1];
        pk[2] = (__bf16)acc[rf][2][2]; pk[3] = (__bf16)acc[rf][2][3];
        *(bf16x4v*)(vTb + dcol * 80 + (rf * 16 + lg * 4) * 2) = pk;
      }
    }
    {  // q: bf16 -> qs [n][64 h] swizzled
#pragma unroll
      for (int rf = 0; rf < 2; ++rf)
#pragma unroll
        for (int r = 0; r < 4; ++r) {
          int n = rf * 16 + lg * 4 + r;
          int off = (n * 128 + (w * 16 + l15) * 2) ^ ((n & 7) << 4);
          *(__bf16*)(qsb + off) = (__bf16)acc[rf][1][r];
        }
    }
    sync_lds();   // overlays visible

    // q readout: coalesced (2048 shorts, 16B/thread)
    {
      unsigned short* qg = qbuf + ((size_t)bs * N_ + n0) * 64;
      int n = t >> 3, c = t & 7;
      int off = (n * 128 + c * 16) ^ ((n & 7) << 4);
      us8 v = *(const us8*)(qsb + off);
      *(us8*)(qg + (size_t)t * 8) = v;
    }

    // fused P^T V (K=32, one step); wave w -> h-frag w
    {
      bf16x8 a2 = *(const bf16x8*)(pTb + (w * 16 + l15) * 80 + lg * 16);
#pragma unroll
      for (int df = 0; df < 4; ++df) {
        bf16x8 b2 = *(const bf16x8*)(vTb + (df * 16 + l15) * 80 + lg * 16);
        nwacc[df] = __builtin_amdgcn_mfma_f32_16x16x32_bf16(a2, b2, nwacc[df], 0, 0, 0);
      }
    }

    // full drain: ALL 8 staging DMAs for the next tile are complete
    // (r14's vmcnt(2) left the 8th DMA outstanding -> stale token rows).
    asm volatile("s_waitcnt vmcnt(0)" ::: "memory");
    sync_lds();   // next tile's buffer ready for all waves
  }

  // write partials: nw bf16 [bs][64][4096], z f32 [bs][64][64]
  {
    size_t base = ((size_t)bs * 64 + slot) * 4096;
#pragma unroll
    for (int df = 0; df < 4; ++df)
#pragma unroll
      for (int r = 0; r < 4; ++r) {
        int h = w * 16 + lg * 4 + r;
        int d = df * 16 + l15;
        pnw[base + h * 64 + d] = f2bf(nwacc[df][r]);
      }
  }
  if (lg == 0)
    pz[((size_t)bs * 64 + slot) * 64 + w * 16 + l15] = zacc;
}

__global__ __launch_bounds__(256) void kB_reduce(
    const unsigned short* __restrict__ pnw, const float* __restrict__ pz,
    float* __restrict__ wfin) {
  int g = blockIdx.x;   // 0..15: idx range [g*256,g*256+256) => h in [g*4,g*4+4)
  int bs = blockIdx.y;  // 0..7
  int t = threadIdx.x;
  int wv = t >> 6, l = t & 63;
  __shared__ float zinv[4];
  int h = g * 4 + wv;
  float z = pz[((size_t)bs * 64 + l) * 64 + h];
#pragma unroll
  for (int m = 32; m; m >>= 1) z += __shfl_xor(z, m);
  if (l == 0) zinv[wv] = 1.f / z;
  __syncthreads();
  int idx = g * 256 + t;
  float ssum = 0.f;
#pragma unroll 8
  for (int p = 0; p < 64; ++p)
    ssum += bf2f(pnw[((size_t)bs * 64 + p) * 4096 + idx]);
  wfin[(size_t)bs * 4096 + idx] = ssum * zinv[wv];
}

__global__ __launch_bounds__(256) void kC_out(
    const unsigned short* __restrict__ qbuf, const float* __restrict__ wfin,
    float* __restrict__ out) {
  int bs = blockIdx.y, b = bs >> 1, s = bs & 1;
  int t = threadIdx.x;
  int w = t >> 6, l = t & 63;
  int l15 = l & 15, lg = l >> 4;
  int tok0 = blockIdx.x * 64;

  __shared__ __align__(16) char cb[16384];
  char* plb = cb;            // P bf16 [64 tok][64 h], swizzled (8K)
  char* wlb = cb + 8192;     // W^T bf16 [64 d][64 h], swizzled (8K)
  float* ob = (float*)cb;    // out f32 [64 tok][64 d] (16K, aliases after MFMA)

  // 1. load w_{1-s}, transpose to [d][h] bf16 swizzled — all 4096 elements
  const float* wsrc = wfin + (size_t)(b * 2 + (1 - s)) * 4096;
#pragma unroll
  for (int rr = 0; rr < 4; ++rr) {
    int fi = t + 256 * rr;        // f32x4 chunk id, [0,1024)
    int h = fi >> 4, d4 = (fi & 15) * 4;
    f32x4 v = *(const f32x4*)(wsrc + h * 64 + d4);
#pragma unroll
    for (int e = 0; e < 4; ++e) {
      int d = d4 + e;
      int off = (d * 128 + h * 2) ^ ((d & 7) << 4);
      *(unsigned short*)(wlb + off) = f2bf(v[e]);
    }
  }

  // 2. q row: exp, quad-reduce sum, normalize, bf16 -> pl
  {
    int tl = t >> 2, p4 = t & 3;
    const unsigned short* qr =
        qbuf + ((size_t)bs * N_ + tok0 + tl) * 64 + p4 * 16;
    us8 u0 = *(const us8*)(qr);
    us8 u1 = *(const us8*)(qr + 8);
    float e[16]; float sum = 0.f;
#pragma unroll
    for (int i = 0; i < 8; ++i) { e[i] = __expf(bf2f(u0[i])); sum += e[i]; }
#pragma unroll
    for (int i = 0; i < 8; ++i) { e[8+i] = __expf(bf2f(u1[i])); sum += e[8+i]; }
    sum += __shfl_xor(sum, 1);
    sum += __shfl_xor(sum, 2);
    float inv = 1.f / sum;
    us8 p0, p1;
#pragma unroll
    for (int i = 0; i < 8; ++i) { p0[i] = f2bf(e[i] * inv); p1[i] = f2bf(e[8+i] * inv); }
    int off = (tl * 128 + p4 * 32) ^ ((tl & 7) << 4);
    *(us8*)(plb + off) = p0;
    *(us8*)(plb + (off ^ 16)) = p1;   // +16 within same 32B chunk (p4*32 has bit4=0)
  }
  __syncthreads();

  // 3. out[64 tok][64 d] = P @ W^T' : 2 K-steps of 16x16x32 MFMA
  f32x4 acc[4];
#pragma unroll
  for (int rf = 0; rf < 4; ++rf) { f32x4 z = {0.f,0.f,0.f,0.f}; acc[rf] = z; }
#pragma unroll
  for (int k2 = 0; k2 < 2; ++k2) {
    int dd = w * 16 + l15;
    int boff = (dd * 128 + (k2 * 32 + lg * 8) * 2) ^ ((dd & 7) << 4);
    bf16x8 bfrag = *(const bf16x8*)(wlb + boff);
#pragma unroll
    for (int rf = 0; rf < 4; ++rf) {
      int row = rf * 16 + l15;
      int aoff = (row * 128 + (k2 * 32 + lg * 8) * 2) ^ ((row & 7) << 4);
      bf16x8 afrag = *(const bf16x8*)(plb + aoff);
      acc[rf] = __builtin_amdgcn_mfma_f32_16x16x32_bf16(afrag, bfrag, acc[rf], 0, 0, 0);
    }
  }
  __syncthreads();   // pl/wl dead; ob takes over

  // 4. fragments -> ob
#pragma unroll
  for (int rf = 0; rf < 4; ++rf)
#pragma unroll
    for (int r = 0; r < 4; ++r) {
      int tok = rf * 16 + lg * 4 + r;
      int d = w * 16 + l15;
      ob[tok * 64 + d] = acc[rf][r];
    }
  __syncthreads();

  // 5. coalesced f32x4 store
  float* outp = out + (size_t)s * ((size_t)B_ * N_ * 64) +
                ((size_t)b * N_ + tok0) * 64;
#pragma unroll
  for (int r2 = 0; r2 < 4; ++r2) {
    int fi = t + 256 * r2;   // 0..1023 f32x4 chunks
    ((f32x4*)outp)[fi] = ((const f32x4*)ob)[fi];
  }
}

extern "C" void kernel_launch(void* const* d_in, const int* in_sizes, int n_in,
                              void* d_out, int out_size, void* d_ws, size_t ws_size,
                              hipStream_t stream) {
  const float* x0  = (const float*)d_in[0];
  const float* x1  = (const float*)d_in[1];
  const float* Wk0 = (const float*)d_in[2];
  const float* Wk1 = (const float*)d_in[3];
  const float* Wq0 = (const float*)d_in[4];
  const float* Wq1 = (const float*)d_in[5];
  const float* Wv0 = (const float*)d_in[6];
  const float* Wv1 = (const float*)d_in[7];
  float* out = (float*)d_out;
  char* wsb = (char*)d_ws;
  unsigned short* wpack = (unsigned short*)(wsb + WPACK_OFF);
  unsigned short* qbuf  = (unsigned short*)(wsb + Q_OFF);
  unsigned short* pnw   = (unsigned short*)(wsb + PNW_OFF);
  float* pz   = (float*)(wsb + PZ_OFF);
  float* wfin = (float*)(wsb + WFIN_OFF);

  kW_pack<<<dim3(384), dim3(256), 0, stream>>>(Wk0, Wk1, Wq0, Wq1, Wv0, Wv1, wpack);
  kP_proj<<<dim3(64, 8), dim3(256), 0, stream>>>(x0, x1, wpack, qbuf, pnw, pz);
  kB_reduce<<<dim3(16, 8), dim3(256), 0, stream>>>(pnw, pz, wfin);
  kC_out<<<dim3(256, 8), dim3(256), 0, stream>>>(qbuf, wfin, out);
}